// Round 3
// baseline (236.663 us; speedup 1.0000x reference)
//
#include <hip/hip_runtime.h>
#include <hip/hip_bf16.h>

typedef __hip_bfloat16 bf16;
typedef __attribute__((ext_vector_type(8))) short short8;   // 8 x bf16 (4 VGPRs) MFMA A/B frag
typedef __attribute__((ext_vector_type(4))) float f32x4;    // MFMA C/D frag

#define AS1 __attribute__((address_space(1)))
#define AS3 __attribute__((address_space(3)))

// async global->LDS, 16B per lane. LDS dst must be wave-uniform base + lane*16.
__device__ __forceinline__ void gld_lds16(const bf16* g, bf16* l) {
    __builtin_amdgcn_global_load_lds((const AS1 void*)g, (AS3 void*)l, 16, 0, 0);
}

// ---------------------------------------------------------------------------
// Kernel 0: f32 -> bf16 down-convert of {prev_hidden, Wu, Wr, We, W_O1..4}
// into d_ws. Flat space of 10,379,264 elems, 8 per thread, 2048 per block.
// Every segment size is divisible by 8 so no thread straddles a boundary.
// ---------------------------------------------------------------------------
__global__ __launch_bounds__(256)
void k_convert(const float* __restrict__ s0,   // prev_hidden  [7340032]
               const float* __restrict__ s1,   // Wu           [802816]
               const float* __restrict__ s2,   // Wr
               const float* __restrict__ s3,   // We
               const float* __restrict__ s4,   // W_O1         [200704]
               const float* __restrict__ s5,   // W_O2         [114688]
               const float* __restrict__ s6,   // W_O3         [200704]
               const float* __restrict__ s7,   // W_O4         [114688]
               bf16* __restrict__ dst)
{
    const size_t B0 =  7340032, B1 =  8142848, B2 =  8945664, B3 = 9748480,
                 B4 =  9949184, B5 = 10063872, B6 = 10264576;
    size_t t = ((size_t)blockIdx.x * 256 + threadIdx.x) * 8;
    const float* s; size_t off;
    if      (t < B0) { s = s0; off = t; }
    else if (t < B1) { s = s1; off = t - B0; }
    else if (t < B2) { s = s2; off = t - B1; }
    else if (t < B3) { s = s3; off = t - B2; }
    else if (t < B4) { s = s4; off = t - B3; }
    else if (t < B5) { s = s5; off = t - B4; }
    else if (t < B6) { s = s6; off = t - B5; }
    else             { s = s7; off = t - B6; }
    float4 a = *(const float4*)(s + off);
    float4 b = *(const float4*)(s + off + 4);
    union { short8 v; bf16 h[8]; } u;
    u.h[0] = (bf16)a.x; u.h[1] = (bf16)a.y; u.h[2] = (bf16)a.z; u.h[3] = (bf16)a.w;
    u.h[4] = (bf16)b.x; u.h[5] = (bf16)b.y; u.h[6] = (bf16)b.z; u.h[7] = (bf16)b.w;
    *(short8*)(dst + t) = u.v;
}

// ---------------------------------------------------------------------------
// Kernel 1: fused gate GEMMs + GRU cell.
//   R_g = prev_hidden @ W_g^T  for g in {u,r,e}   (M=8192, N=896, K=896)
//   block tile 128x64, all 3 gates at once; epilogue does input projections
//   (K=2/3, f32 operands) + sigmoid/tanh + hidden update.
//   hidden written TWICE: f32 -> d_out tail (result), bf16 -> ws (head input).
// ---------------------------------------------------------------------------
__global__ __launch_bounds__(256, 2)
void k_gates(const float* __restrict__ prev_y,    // [8192,2]  f32
             const bf16*  __restrict__ prev_hb,   // [8192,896] bf16 (ws copy)
             const float* __restrict__ prev_hf,   // [8192,896] f32 (original)
             const float* __restrict__ cc,        // [8192,1]  f32
             const bf16*  __restrict__ Wu,        // [896,896] bf16 (ws)
             const bf16*  __restrict__ Wr,
             const bf16*  __restrict__ We,
             const float* __restrict__ Wic,       // [1344,2]  f32
             const float* __restrict__ Wif,       // [1344,3]  f32
             const float* __restrict__ bu_,       // [896]     f32
             const float* __restrict__ br_,
             const float* __restrict__ be_,
             float* __restrict__ hidden_f,        // [8192,896] f32 (d_out tail)
             bf16*  __restrict__ hidden_b)        // [8192,896] bf16 (ws)
{
    __shared__ bf16 At[128 * 64];      // 16 KB, row-major [row][k]
    __shared__ bf16 Bt[3][64 * 64];    // 3 x 8 KB, row-major [n][k]

    const int tid  = threadIdx.x;
    const int wid  = tid >> 6;
    const int lane = tid & 63;
    const int quad = lane >> 4;
    const int l16  = lane & 15;
    const int wm   = (wid >> 1) * 64;  // wave row offset in tile
    const int wn   = (wid & 1) * 32;   // wave col offset in tile
    const int bm   = blockIdx.x;       // 64 row tiles
    const int bn   = blockIdx.y;       // 14 col tiles
    const int srow = tid >> 3;         // staging row 0..31
    const int scol = (tid & 7) * 8;    // staging k-offset (elements)

    const bf16* Wg[3] = {Wu, Wr, We};

    f32x4 acc[3][4][2] = {};

    const size_t a_base = (size_t)(bm * 128) * 896;
    const size_t b_base = (size_t)(bn * 64) * 896;

    for (int k0 = 0; k0 < 896; k0 += 64) {
        __syncthreads();   // protect LDS from readers of previous iter
#pragma unroll
        for (int i = 0; i < 4; ++i) {
            int r = i * 32 + srow;
            gld_lds16(prev_hb + a_base + (size_t)r * 896 + k0 + scol,
                      &At[r * 64 + scol]);
        }
#pragma unroll
        for (int g = 0; g < 3; ++g) {
#pragma unroll
            for (int j = 0; j < 2; ++j) {
                int r = j * 32 + srow;
                gld_lds16(Wg[g] + b_base + (size_t)r * 896 + k0 + scol,
                          &Bt[g][r * 64 + scol]);
            }
        }
        __syncthreads();   // drains vmcnt (global_load_lds) + lgkm

#pragma unroll
        for (int ks = 0; ks < 2; ++ks) {
            short8 af[4];
#pragma unroll
            for (int m = 0; m < 4; ++m)
                af[m] = *(const short8*)&At[(wm + m * 16 + l16) * 64 + ks * 32 + quad * 8];
#pragma unroll
            for (int g = 0; g < 3; ++g) {
#pragma unroll
                for (int n = 0; n < 2; ++n) {
                    short8 bfr = *(const short8*)&Bt[g][(wn + n * 16 + l16) * 64 + ks * 32 + quad * 8];
#pragma unroll
                    for (int m = 0; m < 4; ++m)
                        acc[g][m][n] = __builtin_amdgcn_mfma_f32_16x16x32_bf16(
                            af[m], bfr, acc[g][m][n], 0, 0, 0);
                }
            }
        }
    }

    // ---- epilogue: input projections + gates + hidden update ----
    float wu_[2][3], wr2[2][3], we2[2][3], bu[2], br[2], be[2];
    int hcol[2];
#pragma unroll
    for (int n = 0; n < 2; ++n) {
        int h = bn * 64 + wn + n * 16 + l16;
        hcol[n] = h;
        bu[n] = bu_[h];
        br[n] = br_[h];
        be[n] = be_[h];
        if (h < 448) {     // coarse half: W_Ic [1344,2], rows h / h+448 / h+896
            wu_[n][0] = Wic[h * 2];           wu_[n][1] = Wic[h * 2 + 1];           wu_[n][2] = 0.f;
            wr2[n][0] = Wic[(h + 448) * 2];   wr2[n][1] = Wic[(h + 448) * 2 + 1];   wr2[n][2] = 0.f;
            we2[n][0] = Wic[(h + 896) * 2];   we2[n][1] = Wic[(h + 896) * 2 + 1];   we2[n][2] = 0.f;
        } else {           // fine half: W_If [1344,3]
            int hf = h - 448;
            wu_[n][0] = Wif[hf * 3];           wu_[n][1] = Wif[hf * 3 + 1];           wu_[n][2] = Wif[hf * 3 + 2];
            wr2[n][0] = Wif[(hf + 448) * 3];   wr2[n][1] = Wif[(hf + 448) * 3 + 1];   wr2[n][2] = Wif[(hf + 448) * 3 + 2];
            we2[n][0] = Wif[(hf + 896) * 3];   we2[n][1] = Wif[(hf + 896) * 3 + 1];   we2[n][2] = Wif[(hf + 896) * 3 + 2];
        }
    }
#pragma unroll
    for (int m = 0; m < 4; ++m) {
#pragma unroll
        for (int i = 0; i < 4; ++i) {
            int b = bm * 128 + wm + m * 16 + quad * 4 + i;   // C/D row = quad*4 + reg
            float py0 = prev_y[b * 2];
            float py1 = prev_y[b * 2 + 1];
            float c   = cc[b];
#pragma unroll
            for (int n = 0; n < 2; ++n) {
                float Iu = py0 * wu_[n][0] + py1 * wu_[n][1] + c * wu_[n][2];
                float Ir = py0 * wr2[n][0] + py1 * wr2[n][1] + c * wr2[n][2];
                float Ie = py0 * we2[n][0] + py1 * we2[n][1] + c * we2[n][2];
                float u = 1.f / (1.f + __expf(-(acc[0][m][n][i] + Iu + bu[n])));
                float r = 1.f / (1.f + __expf(-(acc[1][m][n][i] + Ir + br[n])));
                float x = r * acc[2][m][n][i] + Ie + be[n];
                float ex = __expf(2.f * x);
                float e = 1.f - 2.f / (ex + 1.f);             // tanh(x)
                size_t idx = (size_t)b * 896 + hcol[n];
                float ph = prev_hf[idx];
                float hv = u * ph + (1.f - u) * e;
                hidden_f[idx] = hv;            // f32 result (output 2)
                hidden_b[idx] = (bf16)hv;      // bf16 copy for head GEMMs
            }
        }
    }
}

// ---------------------------------------------------------------------------
// Generic GEMM: act(A[M,K] @ B[N,K]^T + bias), A/B bf16, bias f32.
// Output either bf16 (Cb, intermediate) or f32 (Cf, final), per flag.
// ---------------------------------------------------------------------------
__global__ __launch_bounds__(256, 2)
void k_gemm_bt(const bf16* __restrict__ A, int a_stride,
               const bf16* __restrict__ B,           // [N,K] row-major bf16
               const float* __restrict__ bias,       // f32
               bf16* __restrict__ Cb,
               float* __restrict__ Cf,
               int c_stride, int K, int relu)
{
    __shared__ bf16 At[128 * 64];
    __shared__ bf16 Bt[64 * 64];

    const int tid  = threadIdx.x;
    const int wid  = tid >> 6;
    const int lane = tid & 63;
    const int quad = lane >> 4;
    const int l16  = lane & 15;
    const int wm   = (wid >> 1) * 64;
    const int wn   = (wid & 1) * 32;
    const int bm   = blockIdx.x;
    const int bn   = blockIdx.y;
    const int srow = tid >> 3;
    const int scol = (tid & 7) * 8;

    f32x4 acc[4][2] = {};

    const size_t a_base = (size_t)(bm * 128) * a_stride;
    const size_t b_base = (size_t)(bn * 64) * K;

    for (int k0 = 0; k0 < K; k0 += 64) {
        __syncthreads();
#pragma unroll
        for (int i = 0; i < 4; ++i) {
            int r = i * 32 + srow;
            gld_lds16(A + a_base + (size_t)r * a_stride + k0 + scol,
                      &At[r * 64 + scol]);
        }
#pragma unroll
        for (int j = 0; j < 2; ++j) {
            int r = j * 32 + srow;
            gld_lds16(B + b_base + (size_t)r * K + k0 + scol,
                      &Bt[r * 64 + scol]);
        }
        __syncthreads();

#pragma unroll
        for (int ks = 0; ks < 2; ++ks) {
            short8 af[4];
#pragma unroll
            for (int m = 0; m < 4; ++m)
                af[m] = *(const short8*)&At[(wm + m * 16 + l16) * 64 + ks * 32 + quad * 8];
#pragma unroll
            for (int n = 0; n < 2; ++n) {
                short8 bfr = *(const short8*)&Bt[(wn + n * 16 + l16) * 64 + ks * 32 + quad * 8];
#pragma unroll
                for (int m = 0; m < 4; ++m)
                    acc[m][n] = __builtin_amdgcn_mfma_f32_16x16x32_bf16(
                        af[m], bfr, acc[m][n], 0, 0, 0);
            }
        }
    }

#pragma unroll
    for (int n = 0; n < 2; ++n) {
        int h = bn * 64 + wn + n * 16 + l16;
        float bv = bias[h];
#pragma unroll
        for (int m = 0; m < 4; ++m) {
#pragma unroll
            for (int i = 0; i < 4; ++i) {
                int row = bm * 128 + wm + m * 16 + quad * 4 + i;
                float v = acc[m][n][i] + bv;
                if (relu) v = fmaxf(v, 0.f);
                if (Cf) Cf[(size_t)row * c_stride + h] = v;
                else    Cb[(size_t)row * c_stride + h] = (bf16)v;
            }
        }
    }
}

// ---------------------------------------------------------------------------
extern "C" void kernel_launch(void* const* d_in, const int* in_sizes, int n_in,
                              void* d_out, int out_size, void* d_ws, size_t ws_size,
                              hipStream_t stream) {
    const float* prev_y = (const float*)d_in[0];
    const float* prev_h = (const float*)d_in[1];
    const float* cc     = (const float*)d_in[2];
    const float* Wu     = (const float*)d_in[3];
    const float* Wr     = (const float*)d_in[4];
    const float* We     = (const float*)d_in[5];
    const float* Wic    = (const float*)d_in[6];
    const float* Wif    = (const float*)d_in[7];
    const float* W_O1   = (const float*)d_in[8];
    const float* b_O1   = (const float*)d_in[9];
    const float* W_O2   = (const float*)d_in[10];
    const float* b_O2   = (const float*)d_in[11];
    const float* W_O3   = (const float*)d_in[12];
    const float* b_O3   = (const float*)d_in[13];
    const float* W_O4   = (const float*)d_in[14];
    const float* b_O4   = (const float*)d_in[15];
    const float* bias_u = (const float*)d_in[16];
    const float* bias_r = (const float*)d_in[17];
    const float* bias_e = (const float*)d_in[18];

    float* out      = (float*)d_out;
    float* out_c    = out;                                  // [8192,256] f32
    float* out_f    = out + (size_t)8192 * 256;             // [8192,256] f32
    float* hidden_f = out + (size_t)8192 * 512;             // [8192,896] f32

    // ws layout (bf16 elems). inter overlays prev_h_b (dead after k_gates).
    bf16* ws       = (bf16*)d_ws;
    bf16* prev_h_b = ws;                                    // 7,340,032
    bf16* Wu_b     = ws + 7340032;                          //   802,816
    bf16* Wr_b     = ws + 8142848;
    bf16* We_b     = ws + 8945664;
    bf16* W_O1_b   = ws + 9748480;                          //   200,704
    bf16* W_O2_b   = ws + 9949184;                          //   114,688
    bf16* W_O3_b   = ws + 10063872;
    bf16* W_O4_b   = ws + 10264576;
    bf16* hidden_b = ws + 10379264;                         // 7,340,032
    bf16* inter_c  = prev_h_b;                              // 3,670,016 (overlay)
    bf16* inter_f  = prev_h_b + 3670016;                    // 3,670,016 (overlay)

    dim3 blk(256);

    // 0) f32 -> bf16 conversions (10,379,264 elems / 2048 per block = 5068)
    k_convert<<<dim3(5068), blk, 0, stream>>>(prev_h, Wu, Wr, We,
                                              W_O1, W_O2, W_O3, W_O4, ws);

    // 1) gates + hidden (f32 -> d_out tail, bf16 -> ws)
    k_gates<<<dim3(64, 14), blk, 0, stream>>>(prev_y, prev_h_b, prev_h, cc,
                                              Wu_b, Wr_b, We_b,
                                              Wic, Wif, bias_u, bias_r, bias_e,
                                              hidden_f, hidden_b);

    // 2) inter = relu(h_half @ W1^T + b1)   (K=448, N=448), bf16 out
    k_gemm_bt<<<dim3(64, 7), blk, 0, stream>>>(hidden_b,       896, W_O1_b, b_O1, inter_c, nullptr, 448, 448, 1);
    k_gemm_bt<<<dim3(64, 7), blk, 0, stream>>>(hidden_b + 448, 896, W_O3_b, b_O3, inter_f, nullptr, 448, 448, 1);

    // 3) out = inter @ W2^T + b2            (K=448, N=256), f32 out
    k_gemm_bt<<<dim3(64, 4), blk, 0, stream>>>(inter_c, 448, W_O2_b, b_O2, nullptr, out_c, 256, 448, 0);
    k_gemm_bt<<<dim3(64, 4), blk, 0, stream>>>(inter_f, 448, W_O4_b, b_O4, nullptr, out_f, 256, 448, 0);
}

// Round 4
// 218.176 us; speedup vs baseline: 1.0847x; 1.0847x over previous
//
#include <hip/hip_runtime.h>
#include <hip/hip_bf16.h>

typedef __hip_bfloat16 bf16;
typedef __attribute__((ext_vector_type(8))) short short8;   // 8 x bf16 (4 VGPRs) MFMA A/B frag
typedef __attribute__((ext_vector_type(4))) float f32x4;    // MFMA C/D frag

#define AS1 __attribute__((address_space(1)))
#define AS3 __attribute__((address_space(3)))

// async global->LDS, 16B per lane. LDS dst must be wave-uniform base + lane*16.
__device__ __forceinline__ void gld_lds16(const bf16* g, bf16* l) {
    __builtin_amdgcn_global_load_lds((const AS1 void*)g, (AS3 void*)l, 16, 0, 0);
}

// ---------------------------------------------------------------------------
// Kernel 0: f32 -> bf16 down-convert of {prev_hidden, Wu, Wr, We, W_O1..4}
// into d_ws. Flat space of 10,379,264 elems, 8 per thread, 2048 per block.
// ---------------------------------------------------------------------------
__global__ __launch_bounds__(256)
void k_convert(const float* __restrict__ s0,   // prev_hidden  [7340032]
               const float* __restrict__ s1,   // Wu           [802816]
               const float* __restrict__ s2,   // Wr
               const float* __restrict__ s3,   // We
               const float* __restrict__ s4,   // W_O1         [200704]
               const float* __restrict__ s5,   // W_O2         [114688]
               const float* __restrict__ s6,   // W_O3         [200704]
               const float* __restrict__ s7,   // W_O4         [114688]
               bf16* __restrict__ dst)
{
    const size_t B0 =  7340032, B1 =  8142848, B2 =  8945664, B3 = 9748480,
                 B4 =  9949184, B5 = 10063872, B6 = 10264576;
    size_t t = ((size_t)blockIdx.x * 256 + threadIdx.x) * 8;
    const float* s; size_t off;
    if      (t < B0) { s = s0; off = t; }
    else if (t < B1) { s = s1; off = t - B0; }
    else if (t < B2) { s = s2; off = t - B1; }
    else if (t < B3) { s = s3; off = t - B2; }
    else if (t < B4) { s = s4; off = t - B3; }
    else if (t < B5) { s = s5; off = t - B4; }
    else if (t < B6) { s = s6; off = t - B5; }
    else             { s = s7; off = t - B6; }
    float4 a = *(const float4*)(s + off);
    float4 b = *(const float4*)(s + off + 4);
    union { short8 v; bf16 h[8]; } u;
    u.h[0] = (bf16)a.x; u.h[1] = (bf16)a.y; u.h[2] = (bf16)a.z; u.h[3] = (bf16)a.w;
    u.h[4] = (bf16)b.x; u.h[5] = (bf16)b.y; u.h[6] = (bf16)b.z; u.h[7] = (bf16)b.w;
    *(short8*)(dst + t) = u.v;
}

// ---------------------------------------------------------------------------
// Kernel 1: fused gate GEMMs + GRU cell. Tile 128x64, 3 gates at once.
// 96 AGPR acc; launch_bounds(256,3) caps unified regs at 170 -> 3 waves/SIMD.
// ---------------------------------------------------------------------------
__global__ __launch_bounds__(256, 3)
void k_gates(const float* __restrict__ prev_y,    // [8192,2]  f32
             const bf16*  __restrict__ prev_hb,   // [8192,896] bf16 (ws copy)
             const float* __restrict__ prev_hf,   // [8192,896] f32 (original)
             const float* __restrict__ cc,        // [8192,1]  f32
             const bf16*  __restrict__ Wu,        // [896,896] bf16 (ws)
             const bf16*  __restrict__ Wr,
             const bf16*  __restrict__ We,
             const float* __restrict__ Wic,       // [1344,2]  f32
             const float* __restrict__ Wif,       // [1344,3]  f32
             const float* __restrict__ bu_,       // [896]     f32
             const float* __restrict__ br_,
             const float* __restrict__ be_,
             float* __restrict__ hidden_f,        // [8192,896] f32 (d_out tail)
             bf16*  __restrict__ hidden_b)        // [8192,896] bf16 (ws)
{
    __shared__ bf16 At[128 * 64];      // 16 KB, row-major [row][k]
    __shared__ bf16 Bt[3][64 * 64];    // 3 x 8 KB, row-major [n][k]

    const int tid  = threadIdx.x;
    const int wid  = tid >> 6;
    const int lane = tid & 63;
    const int quad = lane >> 4;
    const int l16  = lane & 15;
    const int wm   = (wid >> 1) * 64;  // wave row offset in tile
    const int wn   = (wid & 1) * 32;   // wave col offset in tile
    const int bm   = blockIdx.x;       // 64 row tiles
    const int bn   = blockIdx.y;       // 14 col tiles
    const int srow = tid >> 3;         // staging row 0..31
    const int scol = (tid & 7) * 8;    // staging k-offset (elements)

    const bf16* Wg[3] = {Wu, Wr, We};

    f32x4 acc[3][4][2] = {};

    const size_t a_base = (size_t)(bm * 128) * 896;
    const size_t b_base = (size_t)(bn * 64) * 896;

    for (int k0 = 0; k0 < 896; k0 += 64) {
        __syncthreads();   // protect LDS from readers of previous iter
#pragma unroll
        for (int i = 0; i < 4; ++i) {
            int r = i * 32 + srow;
            gld_lds16(prev_hb + a_base + (size_t)r * 896 + k0 + scol,
                      &At[r * 64 + scol]);
        }
#pragma unroll
        for (int g = 0; g < 3; ++g) {
#pragma unroll
            for (int j = 0; j < 2; ++j) {
                int r = j * 32 + srow;
                gld_lds16(Wg[g] + b_base + (size_t)r * 896 + k0 + scol,
                          &Bt[g][r * 64 + scol]);
            }
        }
        __syncthreads();   // drains vmcnt (global_load_lds) + lgkm

#pragma unroll
        for (int ks = 0; ks < 2; ++ks) {
            short8 af[4];
#pragma unroll
            for (int m = 0; m < 4; ++m)
                af[m] = *(const short8*)&At[(wm + m * 16 + l16) * 64 + ks * 32 + quad * 8];
#pragma unroll
            for (int g = 0; g < 3; ++g) {
#pragma unroll
                for (int n = 0; n < 2; ++n) {
                    short8 bfr = *(const short8*)&Bt[g][(wn + n * 16 + l16) * 64 + ks * 32 + quad * 8];
#pragma unroll
                    for (int m = 0; m < 4; ++m)
                        acc[g][m][n] = __builtin_amdgcn_mfma_f32_16x16x32_bf16(
                            af[m], bfr, acc[g][m][n], 0, 0, 0);
                }
            }
        }
    }

    // ---- epilogue: input projections + gates + hidden update ----
    float wu_[2][3], wr2[2][3], we2[2][3], bu[2], br[2], be[2];
    int hcol[2];
#pragma unroll
    for (int n = 0; n < 2; ++n) {
        int h = bn * 64 + wn + n * 16 + l16;
        hcol[n] = h;
        bu[n] = bu_[h];
        br[n] = br_[h];
        be[n] = be_[h];
        if (h < 448) {     // coarse half: W_Ic [1344,2], rows h / h+448 / h+896
            wu_[n][0] = Wic[h * 2];           wu_[n][1] = Wic[h * 2 + 1];           wu_[n][2] = 0.f;
            wr2[n][0] = Wic[(h + 448) * 2];   wr2[n][1] = Wic[(h + 448) * 2 + 1];   wr2[n][2] = 0.f;
            we2[n][0] = Wic[(h + 896) * 2];   we2[n][1] = Wic[(h + 896) * 2 + 1];   we2[n][2] = 0.f;
        } else {           // fine half: W_If [1344,3]
            int hf = h - 448;
            wu_[n][0] = Wif[hf * 3];           wu_[n][1] = Wif[hf * 3 + 1];           wu_[n][2] = Wif[hf * 3 + 2];
            wr2[n][0] = Wif[(hf + 448) * 3];   wr2[n][1] = Wif[(hf + 448) * 3 + 1];   wr2[n][2] = Wif[(hf + 448) * 3 + 2];
            we2[n][0] = Wif[(hf + 896) * 3];   we2[n][1] = Wif[(hf + 896) * 3 + 1];   we2[n][2] = Wif[(hf + 896) * 3 + 2];
        }
    }
#pragma unroll
    for (int m = 0; m < 4; ++m) {
#pragma unroll
        for (int i = 0; i < 4; ++i) {
            int b = bm * 128 + wm + m * 16 + quad * 4 + i;   // C/D row = quad*4 + reg
            float py0 = prev_y[b * 2];
            float py1 = prev_y[b * 2 + 1];
            float c   = cc[b];
#pragma unroll
            for (int n = 0; n < 2; ++n) {
                float Iu = py0 * wu_[n][0] + py1 * wu_[n][1] + c * wu_[n][2];
                float Ir = py0 * wr2[n][0] + py1 * wr2[n][1] + c * wr2[n][2];
                float Ie = py0 * we2[n][0] + py1 * we2[n][1] + c * we2[n][2];
                float u = 1.f / (1.f + __expf(-(acc[0][m][n][i] + Iu + bu[n])));
                float r = 1.f / (1.f + __expf(-(acc[1][m][n][i] + Ir + br[n])));
                float x = r * acc[2][m][n][i] + Ie + be[n];
                float ex = __expf(2.f * x);
                float e = 1.f - 2.f / (ex + 1.f);             // tanh(x)
                size_t idx = (size_t)b * 896 + hcol[n];
                float ph = prev_hf[idx];
                float hv = u * ph + (1.f - u) * e;
                hidden_f[idx] = hv;            // f32 result (output 2)
                hidden_b[idx] = (bf16)hv;      // bf16 copy for head GEMMs
            }
        }
    }
}

// ---------------------------------------------------------------------------
// Head GEMM, two independent problems merged via blockIdx.z:
//   C[z] = act(A[z][M,K] @ B[z][N,K]^T + bias[z]).  All selects wave-uniform.
// ---------------------------------------------------------------------------
__global__ __launch_bounds__(256, 4)
void k_gemm_bt2(const bf16* __restrict__ A0, const bf16* __restrict__ A1, int a_stride,
                const bf16* __restrict__ B0, const bf16* __restrict__ B1,
                const float* __restrict__ bias0, const float* __restrict__ bias1,
                bf16* __restrict__ Cb0, bf16* __restrict__ Cb1,
                float* __restrict__ Cf0, float* __restrict__ Cf1,
                int c_stride, int K, int relu)
{
    __shared__ bf16 At[128 * 64];
    __shared__ bf16 Bt[64 * 64];

    const int z = blockIdx.z;
    const bf16*  A    = z ? A1 : A0;
    const bf16*  B    = z ? B1 : B0;
    const float* bias = z ? bias1 : bias0;
    bf16*  Cb = z ? Cb1 : Cb0;
    float* Cf = z ? Cf1 : Cf0;

    const int tid  = threadIdx.x;
    const int wid  = tid >> 6;
    const int lane = tid & 63;
    const int quad = lane >> 4;
    const int l16  = lane & 15;
    const int wm   = (wid >> 1) * 64;
    const int wn   = (wid & 1) * 32;
    const int bm   = blockIdx.x;
    const int bn   = blockIdx.y;
    const int srow = tid >> 3;
    const int scol = (tid & 7) * 8;

    f32x4 acc[4][2] = {};

    const size_t a_base = (size_t)(bm * 128) * a_stride;
    const size_t b_base = (size_t)(bn * 64) * K;

    for (int k0 = 0; k0 < K; k0 += 64) {
        __syncthreads();
#pragma unroll
        for (int i = 0; i < 4; ++i) {
            int r = i * 32 + srow;
            gld_lds16(A + a_base + (size_t)r * a_stride + k0 + scol,
                      &At[r * 64 + scol]);
        }
#pragma unroll
        for (int j = 0; j < 2; ++j) {
            int r = j * 32 + srow;
            gld_lds16(B + b_base + (size_t)r * K + k0 + scol,
                      &Bt[r * 64 + scol]);
        }
        __syncthreads();

#pragma unroll
        for (int ks = 0; ks < 2; ++ks) {
            short8 af[4];
#pragma unroll
            for (int m = 0; m < 4; ++m)
                af[m] = *(const short8*)&At[(wm + m * 16 + l16) * 64 + ks * 32 + quad * 8];
#pragma unroll
            for (int n = 0; n < 2; ++n) {
                short8 bfr = *(const short8*)&Bt[(wn + n * 16 + l16) * 64 + ks * 32 + quad * 8];
#pragma unroll
                for (int m = 0; m < 4; ++m)
                    acc[m][n] = __builtin_amdgcn_mfma_f32_16x16x32_bf16(
                        af[m], bfr, acc[m][n], 0, 0, 0);
            }
        }
    }

#pragma unroll
    for (int n = 0; n < 2; ++n) {
        int h = bn * 64 + wn + n * 16 + l16;
        float bv = bias[h];
#pragma unroll
        for (int m = 0; m < 4; ++m) {
#pragma unroll
            for (int i = 0; i < 4; ++i) {
                int row = bm * 128 + wm + m * 16 + quad * 4 + i;
                float v = acc[m][n][i] + bv;
                if (relu) v = fmaxf(v, 0.f);
                if (Cf) Cf[(size_t)row * c_stride + h] = v;
                else    Cb[(size_t)row * c_stride + h] = (bf16)v;
            }
        }
    }
}

// ---------------------------------------------------------------------------
extern "C" void kernel_launch(void* const* d_in, const int* in_sizes, int n_in,
                              void* d_out, int out_size, void* d_ws, size_t ws_size,
                              hipStream_t stream) {
    const float* prev_y = (const float*)d_in[0];
    const float* prev_h = (const float*)d_in[1];
    const float* cc     = (const float*)d_in[2];
    const float* Wu     = (const float*)d_in[3];
    const float* Wr     = (const float*)d_in[4];
    const float* We     = (const float*)d_in[5];
    const float* Wic    = (const float*)d_in[6];
    const float* Wif    = (const float*)d_in[7];
    const float* W_O1   = (const float*)d_in[8];
    const float* b_O1   = (const float*)d_in[9];
    const float* W_O2   = (const float*)d_in[10];
    const float* b_O2   = (const float*)d_in[11];
    const float* W_O3   = (const float*)d_in[12];
    const float* b_O3   = (const float*)d_in[13];
    const float* W_O4   = (const float*)d_in[14];
    const float* b_O4   = (const float*)d_in[15];
    const float* bias_u = (const float*)d_in[16];
    const float* bias_r = (const float*)d_in[17];
    const float* bias_e = (const float*)d_in[18];

    float* out      = (float*)d_out;
    float* out_c    = out;                                  // [8192,256] f32
    float* out_f    = out + (size_t)8192 * 256;             // [8192,256] f32
    float* hidden_f = out + (size_t)8192 * 512;             // [8192,896] f32

    // ws layout (bf16 elems). inter overlays prev_h_b (dead after k_gates).
    bf16* ws       = (bf16*)d_ws;
    bf16* prev_h_b = ws;                                    // 7,340,032
    bf16* Wu_b     = ws + 7340032;                          //   802,816
    bf16* Wr_b     = ws + 8142848;
    bf16* We_b     = ws + 8945664;
    bf16* W_O1_b   = ws + 9748480;                          //   200,704
    bf16* W_O2_b   = ws + 9949184;                          //   114,688
    bf16* W_O3_b   = ws + 10063872;
    bf16* W_O4_b   = ws + 10264576;
    bf16* hidden_b = ws + 10379264;                         // 7,340,032
    bf16* inter_c  = prev_h_b;                              // 3,670,016 (overlay)
    bf16* inter_f  = prev_h_b + 3670016;                    // 3,670,016 (overlay)

    dim3 blk(256);

    // 0) f32 -> bf16 conversions (10,379,264 elems / 2048 per block = 5068)
    k_convert<<<dim3(5068), blk, 0, stream>>>(prev_h, Wu, Wr, We,
                                              W_O1, W_O2, W_O3, W_O4, ws);

    // 1) gates + hidden (f32 -> d_out tail, bf16 -> ws)
    k_gates<<<dim3(64, 14), blk, 0, stream>>>(prev_y, prev_h_b, prev_h, cc,
                                              Wu_b, Wr_b, We_b,
                                              Wic, Wif, bias_u, bias_r, bias_e,
                                              hidden_f, hidden_b);

    // 2) inter = relu(h_half @ W1^T + b1)   (K=448, N=448), bf16 out, both heads
    k_gemm_bt2<<<dim3(64, 7, 2), blk, 0, stream>>>(
        hidden_b, hidden_b + 448, 896,
        W_O1_b, W_O3_b, b_O1, b_O3,
        inter_c, inter_f, nullptr, nullptr, 448, 448, 1);

    // 3) out = inter @ W2^T + b2            (K=448, N=256), f32 out, both heads
    k_gemm_bt2<<<dim3(64, 4, 2), blk, 0, stream>>>(
        inter_c, inter_f, 448,
        W_O2_b, W_O4_b, b_O2, b_O4,
        nullptr, nullptr, out_c, out_f, 256, 448, 0);
}

// Round 5
// 206.658 us; speedup vs baseline: 1.1452x; 1.0557x over previous
//
#include <hip/hip_runtime.h>
#include <hip/hip_bf16.h>

typedef __hip_bfloat16 bf16;
typedef __attribute__((ext_vector_type(8))) short short8;   // 8 x bf16 (4 VGPRs) MFMA A/B frag
typedef __attribute__((ext_vector_type(4))) float f32x4;    // MFMA C/D frag

#define AS1 __attribute__((address_space(1)))
#define AS3 __attribute__((address_space(3)))

// async global->LDS, 16B per lane. LDS dst must be wave-uniform base + lane*16.
__device__ __forceinline__ void gld_lds16(const bf16* g, bf16* l) {
    __builtin_amdgcn_global_load_lds((const AS1 void*)g, (AS3 void*)l, 16, 0, 0);
}

// XOR bank swizzle: LDS physical 16B-chunk p of row r holds global chunk p^(r&7).
// Writers fetch global chunk (p ^ (r&7)); readers of logical chunk c use p = c^(r&7).
// Spreads the 128B-row-stride frag reads across 8 bank groups (16-way -> ~8-way).

// ---------------------------------------------------------------------------
// Kernel 0: f32 -> bf16 down-convert of {prev_hidden, Wu, Wr, We, W_O1..4}
// into d_ws. Flat space of 10,379,264 elems, 8 per thread, 2048 per block.
// ---------------------------------------------------------------------------
__global__ __launch_bounds__(256)
void k_convert(const float* __restrict__ s0,   // prev_hidden  [7340032]
               const float* __restrict__ s1,   // Wu           [802816]
               const float* __restrict__ s2,   // Wr
               const float* __restrict__ s3,   // We
               const float* __restrict__ s4,   // W_O1         [200704]
               const float* __restrict__ s5,   // W_O2         [114688]
               const float* __restrict__ s6,   // W_O3         [200704]
               const float* __restrict__ s7,   // W_O4         [114688]
               bf16* __restrict__ dst)
{
    const size_t B0 =  7340032, B1 =  8142848, B2 =  8945664, B3 = 9748480,
                 B4 =  9949184, B5 = 10063872, B6 = 10264576;
    size_t t = ((size_t)blockIdx.x * 256 + threadIdx.x) * 8;
    const float* s; size_t off;
    if      (t < B0) { s = s0; off = t; }
    else if (t < B1) { s = s1; off = t - B0; }
    else if (t < B2) { s = s2; off = t - B1; }
    else if (t < B3) { s = s3; off = t - B2; }
    else if (t < B4) { s = s4; off = t - B3; }
    else if (t < B5) { s = s5; off = t - B4; }
    else if (t < B6) { s = s6; off = t - B5; }
    else             { s = s7; off = t - B6; }
    float4 a = *(const float4*)(s + off);
    float4 b = *(const float4*)(s + off + 4);
    union { short8 v; bf16 h[8]; } u;
    u.h[0] = (bf16)a.x; u.h[1] = (bf16)a.y; u.h[2] = (bf16)a.z; u.h[3] = (bf16)a.w;
    u.h[4] = (bf16)b.x; u.h[5] = (bf16)b.y; u.h[6] = (bf16)b.z; u.h[7] = (bf16)b.w;
    *(short8*)(dst + t) = u.v;
}

// ---------------------------------------------------------------------------
// Kernel 1: fused gate GEMMs + GRU cell. Tile 128x64, 3 gates at once.
// ---------------------------------------------------------------------------
__global__ __launch_bounds__(256, 2)
void k_gates(const float* __restrict__ prev_y,    // [8192,2]  f32
             const bf16*  __restrict__ prev_hb,   // [8192,896] bf16 (ws copy)
             const float* __restrict__ prev_hf,   // [8192,896] f32 (original)
             const float* __restrict__ cc,        // [8192,1]  f32
             const bf16*  __restrict__ Wu,        // [896,896] bf16 (ws)
             const bf16*  __restrict__ Wr,
             const bf16*  __restrict__ We,
             const float* __restrict__ Wic,       // [1344,2]  f32
             const float* __restrict__ Wif,       // [1344,3]  f32
             const float* __restrict__ bu_,       // [896]     f32
             const float* __restrict__ br_,
             const float* __restrict__ be_,
             float* __restrict__ hidden_f,        // [8192,896] f32 (d_out tail)
             bf16*  __restrict__ hidden_b)        // [8192,896] bf16 (ws)
{
    __shared__ bf16 At[128 * 64];      // 16 KB, row-major [row][k], XOR-swizzled chunks
    __shared__ bf16 Bt[3][64 * 64];    // 3 x 8 KB, row-major [n][k], XOR-swizzled

    const int tid  = threadIdx.x;
    const int wid  = tid >> 6;
    const int lane = tid & 63;
    const int quad = lane >> 4;
    const int l16  = lane & 15;
    const int sw   = l16 & 7;          // reader swizzle key (row&7 == l16&7 here)
    const int wm   = (wid >> 1) * 64;  // wave row offset in tile
    const int wn   = (wid & 1) * 32;   // wave col offset in tile
    const int bm   = blockIdx.x;       // 64 row tiles
    const int bn   = blockIdx.y;       // 14 col tiles
    const int srow = tid >> 3;         // staging row 0..31
    const int sp   = tid & 7;          // staging physical chunk 0..7
    const int scol = sp * 8;           // LDS k-offset (elements)
    const int gcol = ((sp ^ (srow & 7)) * 8);  // swizzled global k-offset

    const bf16* Wg[3] = {Wu, Wr, We};

    f32x4 acc[3][4][2] = {};

    const size_t a_base = (size_t)(bm * 128) * 896;
    const size_t b_base = (size_t)(bn * 64) * 896;

    for (int k0 = 0; k0 < 896; k0 += 64) {
        __syncthreads();   // protect LDS from readers of previous iter
#pragma unroll
        for (int i = 0; i < 4; ++i) {
            int r = i * 32 + srow;     // i*32 doesn't change r&7 == srow&7
            gld_lds16(prev_hb + a_base + (size_t)r * 896 + k0 + gcol,
                      &At[r * 64 + scol]);
        }
#pragma unroll
        for (int g = 0; g < 3; ++g) {
#pragma unroll
            for (int j = 0; j < 2; ++j) {
                int r = j * 32 + srow;
                gld_lds16(Wg[g] + b_base + (size_t)r * 896 + k0 + gcol,
                          &Bt[g][r * 64 + scol]);
            }
        }
        __syncthreads();   // drains vmcnt (global_load_lds) + lgkm

#pragma unroll
        for (int ks = 0; ks < 2; ++ks) {
            const int pk = ((ks * 4 + quad) ^ sw) * 8;   // physical chunk offset (elems)
            short8 af[4];
#pragma unroll
            for (int m = 0; m < 4; ++m)
                af[m] = *(const short8*)&At[(wm + m * 16 + l16) * 64 + pk];
#pragma unroll
            for (int g = 0; g < 3; ++g) {
#pragma unroll
                for (int n = 0; n < 2; ++n) {
                    short8 bfr = *(const short8*)&Bt[g][(wn + n * 16 + l16) * 64 + pk];
#pragma unroll
                    for (int m = 0; m < 4; ++m)
                        acc[g][m][n] = __builtin_amdgcn_mfma_f32_16x16x32_bf16(
                            af[m], bfr, acc[g][m][n], 0, 0, 0);
                }
            }
        }
    }

    // ---- epilogue: input projections + gates + hidden update ----
    float wu_[2][3], wr2[2][3], we2[2][3], bu[2], br[2], be[2];
    int hcol[2];
#pragma unroll
    for (int n = 0; n < 2; ++n) {
        int h = bn * 64 + wn + n * 16 + l16;
        hcol[n] = h;
        bu[n] = bu_[h];
        br[n] = br_[h];
        be[n] = be_[h];
        if (h < 448) {     // coarse half: W_Ic [1344,2], rows h / h+448 / h+896
            wu_[n][0] = Wic[h * 2];           wu_[n][1] = Wic[h * 2 + 1];           wu_[n][2] = 0.f;
            wr2[n][0] = Wic[(h + 448) * 2];   wr2[n][1] = Wic[(h + 448) * 2 + 1];   wr2[n][2] = 0.f;
            we2[n][0] = Wic[(h + 896) * 2];   we2[n][1] = Wic[(h + 896) * 2 + 1];   we2[n][2] = 0.f;
        } else {           // fine half: W_If [1344,3]
            int hf = h - 448;
            wu_[n][0] = Wif[hf * 3];           wu_[n][1] = Wif[hf * 3 + 1];           wu_[n][2] = Wif[hf * 3 + 2];
            wr2[n][0] = Wif[(hf + 448) * 3];   wr2[n][1] = Wif[(hf + 448) * 3 + 1];   wr2[n][2] = Wif[(hf + 448) * 3 + 2];
            we2[n][0] = Wif[(hf + 896) * 3];   we2[n][1] = Wif[(hf + 896) * 3 + 1];   we2[n][2] = Wif[(hf + 896) * 3 + 2];
        }
    }
#pragma unroll
    for (int m = 0; m < 4; ++m) {
#pragma unroll
        for (int i = 0; i < 4; ++i) {
            int b = bm * 128 + wm + m * 16 + quad * 4 + i;   // C/D row = quad*4 + reg
            float py0 = prev_y[b * 2];
            float py1 = prev_y[b * 2 + 1];
            float c   = cc[b];
#pragma unroll
            for (int n = 0; n < 2; ++n) {
                float Iu = py0 * wu_[n][0] + py1 * wu_[n][1] + c * wu_[n][2];
                float Ir = py0 * wr2[n][0] + py1 * wr2[n][1] + c * wr2[n][2];
                float Ie = py0 * we2[n][0] + py1 * we2[n][1] + c * we2[n][2];
                float u = 1.f / (1.f + __expf(-(acc[0][m][n][i] + Iu + bu[n])));
                float r = 1.f / (1.f + __expf(-(acc[1][m][n][i] + Ir + br[n])));
                float x = r * acc[2][m][n][i] + Ie + be[n];
                float ex = __expf(2.f * x);
                float e = 1.f - 2.f / (ex + 1.f);             // tanh(x)
                size_t idx = (size_t)b * 896 + hcol[n];
                float ph = prev_hf[idx];
                float hv = u * ph + (1.f - u) * e;
                hidden_f[idx] = hv;            // f32 result (output 2)
                hidden_b[idx] = (bf16)hv;      // bf16 copy for head GEMMs
            }
        }
    }
}

// ---------------------------------------------------------------------------
// Head GEMM, two independent problems merged via blockIdx.z:
//   C[z] = act(A[z][M,K] @ B[z][N,K]^T + bias[z]).  All selects wave-uniform.
// ---------------------------------------------------------------------------
__global__ __launch_bounds__(256, 4)
void k_gemm_bt2(const bf16* __restrict__ A0, const bf16* __restrict__ A1, int a_stride,
                const bf16* __restrict__ B0, const bf16* __restrict__ B1,
                const float* __restrict__ bias0, const float* __restrict__ bias1,
                bf16* __restrict__ Cb0, bf16* __restrict__ Cb1,
                float* __restrict__ Cf0, float* __restrict__ Cf1,
                int c_stride, int K, int relu)
{
    __shared__ bf16 At[128 * 64];
    __shared__ bf16 Bt[64 * 64];

    const int z = blockIdx.z;
    const bf16*  A    = z ? A1 : A0;
    const bf16*  B    = z ? B1 : B0;
    const float* bias = z ? bias1 : bias0;
    bf16*  Cb = z ? Cb1 : Cb0;
    float* Cf = z ? Cf1 : Cf0;

    const int tid  = threadIdx.x;
    const int wid  = tid >> 6;
    const int lane = tid & 63;
    const int quad = lane >> 4;
    const int l16  = lane & 15;
    const int sw   = l16 & 7;
    const int wm   = (wid >> 1) * 64;
    const int wn   = (wid & 1) * 32;
    const int bm   = blockIdx.x;
    const int bn   = blockIdx.y;
    const int srow = tid >> 3;
    const int sp   = tid & 7;
    const int scol = sp * 8;
    const int gcol = ((sp ^ (srow & 7)) * 8);

    f32x4 acc[4][2] = {};

    const size_t a_base = (size_t)(bm * 128) * a_stride;
    const size_t b_base = (size_t)(bn * 64) * K;

    for (int k0 = 0; k0 < K; k0 += 64) {
        __syncthreads();
#pragma unroll
        for (int i = 0; i < 4; ++i) {
            int r = i * 32 + srow;
            gld_lds16(A + a_base + (size_t)r * a_stride + k0 + gcol,
                      &At[r * 64 + scol]);
        }
#pragma unroll
        for (int j = 0; j < 2; ++j) {
            int r = j * 32 + srow;
            gld_lds16(B + b_base + (size_t)r * K + k0 + gcol,
                      &Bt[r * 64 + scol]);
        }
        __syncthreads();

#pragma unroll
        for (int ks = 0; ks < 2; ++ks) {
            const int pk = ((ks * 4 + quad) ^ sw) * 8;
            short8 af[4];
#pragma unroll
            for (int m = 0; m < 4; ++m)
                af[m] = *(const short8*)&At[(wm + m * 16 + l16) * 64 + pk];
#pragma unroll
            for (int n = 0; n < 2; ++n) {
                short8 bfr = *(const short8*)&Bt[(wn + n * 16 + l16) * 64 + pk];
#pragma unroll
                for (int m = 0; m < 4; ++m)
                    acc[m][n] = __builtin_amdgcn_mfma_f32_16x16x32_bf16(
                        af[m], bfr, acc[m][n], 0, 0, 0);
            }
        }
    }

#pragma unroll
    for (int n = 0; n < 2; ++n) {
        int h = bn * 64 + wn + n * 16 + l16;
        float bv = bias[h];
#pragma unroll
        for (int m = 0; m < 4; ++m) {
#pragma unroll
            for (int i = 0; i < 4; ++i) {
                int row = bm * 128 + wm + m * 16 + quad * 4 + i;
                float v = acc[m][n][i] + bv;
                if (relu) v = fmaxf(v, 0.f);
                if (Cf) Cf[(size_t)row * c_stride + h] = v;
                else    Cb[(size_t)row * c_stride + h] = (bf16)v;
            }
        }
    }
}

// ---------------------------------------------------------------------------
extern "C" void kernel_launch(void* const* d_in, const int* in_sizes, int n_in,
                              void* d_out, int out_size, void* d_ws, size_t ws_size,
                              hipStream_t stream) {
    const float* prev_y = (const float*)d_in[0];
    const float* prev_h = (const float*)d_in[1];
    const float* cc     = (const float*)d_in[2];
    const float* Wu     = (const float*)d_in[3];
    const float* Wr     = (const float*)d_in[4];
    const float* We     = (const float*)d_in[5];
    const float* Wic    = (const float*)d_in[6];
    const float* Wif    = (const float*)d_in[7];
    const float* W_O1   = (const float*)d_in[8];
    const float* b_O1   = (const float*)d_in[9];
    const float* W_O2   = (const float*)d_in[10];
    const float* b_O2   = (const float*)d_in[11];
    const float* W_O3   = (const float*)d_in[12];
    const float* b_O3   = (const float*)d_in[13];
    const float* W_O4   = (const float*)d_in[14];
    const float* b_O4   = (const float*)d_in[15];
    const float* bias_u = (const float*)d_in[16];
    const float* bias_r = (const float*)d_in[17];
    const float* bias_e = (const float*)d_in[18];

    float* out      = (float*)d_out;
    float* out_c    = out;                                  // [8192,256] f32
    float* out_f    = out + (size_t)8192 * 256;             // [8192,256] f32
    float* hidden_f = out + (size_t)8192 * 512;             // [8192,896] f32

    // ws layout (bf16 elems). inter overlays prev_h_b (dead after k_gates).
    bf16* ws       = (bf16*)d_ws;
    bf16* prev_h_b = ws;                                    // 7,340,032
    bf16* Wu_b     = ws + 7340032;                          //   802,816
    bf16* Wr_b     = ws + 8142848;
    bf16* We_b     = ws + 8945664;
    bf16* W_O1_b   = ws + 9748480;                          //   200,704
    bf16* W_O2_b   = ws + 9949184;                          //   114,688
    bf16* W_O3_b   = ws + 10063872;
    bf16* W_O4_b   = ws + 10264576;
    bf16* hidden_b = ws + 10379264;                         // 7,340,032
    bf16* inter_c  = prev_h_b;                              // 3,670,016 (overlay)
    bf16* inter_f  = prev_h_b + 3670016;                    // 3,670,016 (overlay)

    dim3 blk(256);

    // 0) f32 -> bf16 conversions (10,379,264 elems / 2048 per block = 5068)
    k_convert<<<dim3(5068), blk, 0, stream>>>(prev_h, Wu, Wr, We,
                                              W_O1, W_O2, W_O3, W_O4, ws);

    // 1) gates + hidden (f32 -> d_out tail, bf16 -> ws)
    k_gates<<<dim3(64, 14), blk, 0, stream>>>(prev_y, prev_h_b, prev_h, cc,
                                              Wu_b, Wr_b, We_b,
                                              Wic, Wif, bias_u, bias_r, bias_e,
                                              hidden_f, hidden_b);

    // 2) inter = relu(h_half @ W1^T + b1)   (K=448, N=448), bf16 out, both heads
    k_gemm_bt2<<<dim3(64, 7, 2), blk, 0, stream>>>(
        hidden_b, hidden_b + 448, 896,
        W_O1_b, W_O3_b, b_O1, b_O3,
        inter_c, inter_f, nullptr, nullptr, 448, 448, 1);

    // 3) out = inter @ W2^T + b2            (K=448, N=256), f32 out, both heads
    k_gemm_bt2<<<dim3(64, 4, 2), blk, 0, stream>>>(
        inter_c, inter_f, 448,
        W_O2_b, W_O4_b, b_O2, b_O4,
        nullptr, nullptr, out_c, out_f, 256, 448, 0);
}